// Round 2
// baseline (1051.873 us; speedup 1.0000x reference)
//
#include <hip/hip_runtime.h>
#include <hip/hip_bf16.h>

typedef unsigned int u32;
typedef unsigned short u16;

#define B_   32
#define S_   512
#define H_   256
#define NH_  8
#define HD_  32

// ---------- bf16 helpers (bf16 = high 16 bits of f32) ----------
__device__ __forceinline__ float bfl(u32 u){ union{u32 i;float f;} c; c.i = u << 16;          return c.f; }
__device__ __forceinline__ float bfh(u32 u){ union{u32 i;float f;} c; c.i = u & 0xffff0000u;  return c.f; }
__device__ __forceinline__ float bf1(u16 u){ union{u32 i;float f;} c; c.i = ((u32)u) << 16;   return c.f; }
__device__ __forceinline__ u16   f2b(float f){ __hip_bfloat16 h = __float2bfloat16(f); return *reinterpret_cast<u16*>(&h); }
__device__ __forceinline__ void  unp8(const uint4 u, float* f){
  f[0]=bfl(u.x); f[1]=bfh(u.x); f[2]=bfl(u.y); f[3]=bfh(u.y);
  f[4]=bfl(u.z); f[5]=bfh(u.z); f[6]=bfl(u.w); f[7]=bfh(u.w);
}

// ---------- dtype-polymorphic loads (F32=1: float data, F32=0: bf16 data) ----------
template<int F32>
__device__ __forceinline__ void load8(const void* p, int e8, float* f) {  // e8 = element_offset/8
  if (F32) {
    const float4* q = (const float4*)p;
    const float4 a = q[e8 * 2], b = q[e8 * 2 + 1];
    f[0]=a.x; f[1]=a.y; f[2]=a.z; f[3]=a.w; f[4]=b.x; f[5]=b.y; f[6]=b.z; f[7]=b.w;
  } else {
    unp8(((const uint4*)p)[e8], f);
  }
}
template<int F32>
__device__ __forceinline__ float load1(const void* p, size_t e) {
  return F32 ? ((const float*)p)[e] : bf1(((const u16*)p)[e]);
}
template<int F32>
__device__ __forceinline__ void store1(void* p, size_t e, float v) {
  if (F32) ((float*)p)[e] = v; else ((u16*)p)[e] = f2b(v);
}

// ---------- in-kernel dtype sniff over first 4KB of `inputs` ----------
// bf16 pairs: bits 14..7 of each u32 are a bf16 exponent (~[100,135] for N(0,1) data, ~100% hits)
// f32:        bits 14..7 are mid-mantissa (uniform, ~14% hits). 1024 samples -> 33 sigma gap.
__device__ __forceinline__ int sniff_mode(const void* xin) {   // returns 0=bf16, 1=f32
  __shared__ int votes;
  const int tid = threadIdx.x;
  if (tid == 0) votes = 0;
  __syncthreads();
  const u32* xw = (const u32*)xin;
  int h = 0;
#pragma unroll
  for (int j = 0; j < 4; ++j) {
    const u32 u = xw[(tid << 2) + j];
    const u32 e = (u >> 7) & 0xFF;
    h += (e >= 100 && e <= 135) ? 1 : 0;
  }
  if (h) atomicAdd(&votes, h);
  __syncthreads();
  return (votes >= 512) ? 0 : 1;
}

// ============================================================
// Kernel 1: LayerNorm + QKV projection + head transforms
// 8 rows per block, 256 threads. Outputs q,k,v bf16 [B*NH][S][HD].
// ============================================================
template<int F32>
__global__ __launch_bounds__(256) void ln_qkv_kernel(
    const void* __restrict__ xin,   // [B*S*H]
    const void* __restrict__ rmask, // [B*S]
    const void* __restrict__ wi,    // [3H][H]
    const void* __restrict__ gamma, // [H]
    const void* __restrict__ beta,  // [H]
    u16* __restrict__ qbuf, u16* __restrict__ kbuf, u16* __restrict__ vbuf)
{
  if (sniff_mode(xin) != F32) return;

  __shared__ __align__(16) float xn[8][256];
  __shared__ float lmr[8];
  const int tid = threadIdx.x;
  const int r   = tid >> 5;      // row within block (0..7)
  const int ln  = tid & 31;      // lane within row-group
  const int grow = blockIdx.x * 8 + r;

  // ---- LayerNorm (32 lanes per row, 8 elems each) ----
  float x[8]; load8<F32>(xin, grow * 32 + ln, x);
  float s = 0.f, sq = 0.f;
#pragma unroll
  for (int j = 0; j < 8; ++j) { s += x[j]; sq += x[j] * x[j]; }
#pragma unroll
  for (int m = 1; m < 32; m <<= 1) { s += __shfl_xor(s, m); sq += __shfl_xor(sq, m); }
  const float mu  = s * (1.f / 256.f);
  const float var = sq * (1.f / 256.f) - mu * mu;
  const float rs  = rsqrtf(var + 1e-5f);
  float g[8], bb[8];
  load8<F32>(gamma, ln, g);
  load8<F32>(beta,  ln, bb);
#pragma unroll
  for (int j = 0; j < 8; ++j) xn[r][ln * 8 + j] = (x[j] - mu) * rs * g[j] + bb[j];
  if (ln == 0) lmr[r] = logf(load1<F32>(rmask, grow));
  __syncthreads();

  // ---- QKV: thread tid computes output dim tid for q,k,v across 8 rows ----
  float acc0[8] = {0.f}, acc1[8] = {0.f}, acc2[8] = {0.f};
  const int ro0 = tid * 32, ro1 = (tid + 256) * 32, ro2 = (tid + 512) * 32;
  for (int i8 = 0; i8 < 32; ++i8) {
    float wq8[8], wk8[8], wv8[8];
    load8<F32>(wi, ro0 + i8, wq8);
    load8<F32>(wi, ro1 + i8, wk8);
    load8<F32>(wi, ro2 + i8, wv8);
    const int i = i8 * 8;
#pragma unroll
    for (int rr = 0; rr < 8; ++rr) {
      const float4 xa = *(const float4*)&xn[rr][i];
      const float4 xb = *(const float4*)&xn[rr][i + 4];
      acc0[rr] += xa.x*wq8[0] + xa.y*wq8[1] + xa.z*wq8[2] + xa.w*wq8[3]
                + xb.x*wq8[4] + xb.y*wq8[5] + xb.z*wq8[6] + xb.w*wq8[7];
      acc1[rr] += xa.x*wk8[0] + xa.y*wk8[1] + xa.z*wk8[2] + xa.w*wk8[3]
                + xb.x*wk8[4] + xb.y*wk8[5] + xb.z*wk8[6] + xb.w*wk8[7];
      acc2[rr] += xa.x*wv8[0] + xa.y*wv8[1] + xa.z*wv8[2] + xa.w*wv8[3]
                + xb.x*wv8[4] + xb.y*wv8[5] + xb.z*wv8[6] + xb.w*wv8[7];
    }
  }

  // ---- transforms + store head-major ----
  const int head = tid >> 5, d = tid & 31;
#pragma unroll
  for (int rr = 0; rr < 8; ++rr) {
    const int gr = blockIdx.x * 8 + rr;
    const int b = gr >> 9, ss = gr & 511;
    const size_t base = ((size_t)(b * NH_ + head) * S_ + ss) * HD_ + d;
    float qv = acc0[rr]; qv = qv * qv + 1e-6f;
    qbuf[base] = f2b(qv);
    kbuf[base] = f2b(acc1[rr] + lmr[rr]);
    vbuf[base] = f2b(acc2[rr]);
  }
}

// ============================================================
// Kernel 2: attention per (bh, query-half). 256 threads, 64KB LDS.
// KT[32][512] bf16 (d-major), V2[16][512] u32 (d-pair-major).
// One wave processes 2 queries at a time (register-blocked).
// Mode-independent: q/k/v intermediates are always bf16.
// ============================================================
__global__ __launch_bounds__(256) void attn_kernel(
    const u16* __restrict__ qbuf, const u16* __restrict__ kbuf,
    const u16* __restrict__ vbuf, u16* __restrict__ ctx)
{
  __shared__ __align__(16) u16 KT[32 * 512];
  __shared__ __align__(16) u32 V2[16 * 512];
  const int tid = threadIdx.x;
  const int bh = blockIdx.x >> 1;
  const int qhalf = blockIdx.x & 1;
  const int l = tid & 63, w = tid >> 6;
  const size_t base = (size_t)bh * (S_ * HD_);

  // ---- stage K (transposed) and V (d-pair major) ----
  const uint4* ks = (const uint4*)(kbuf + base);
  const uint4* vs = (const uint4*)(vbuf + base);
  for (int it = 0; it < 8; ++it) {
    const int e8 = tid + it * 256;        // uint4 index: 8 bf16
    const uint4 kk = ks[e8];
    const uint4 vv = vs[e8];
    const int sI = e8 >> 2;               // key index
    const int d0 = (e8 & 3) * 8;          // first dim of the 8
    KT[(d0+0)*512+sI] = (u16)(kk.x & 0xffff); KT[(d0+1)*512+sI] = (u16)(kk.x >> 16);
    KT[(d0+2)*512+sI] = (u16)(kk.y & 0xffff); KT[(d0+3)*512+sI] = (u16)(kk.y >> 16);
    KT[(d0+4)*512+sI] = (u16)(kk.z & 0xffff); KT[(d0+5)*512+sI] = (u16)(kk.z >> 16);
    KT[(d0+6)*512+sI] = (u16)(kk.w & 0xffff); KT[(d0+7)*512+sI] = (u16)(kk.w >> 16);
    const int dp = (e8 & 3) * 4;
    V2[(dp+0)*512+sI] = vv.x; V2[(dp+1)*512+sI] = vv.y;
    V2[(dp+2)*512+sI] = vv.z; V2[(dp+3)*512+sI] = vv.w;
  }
  __syncthreads();

  const int d2h = l & 15, c = l >> 4;     // PV mapping: dim-pair, key-quarter
  const int q0 = qhalf * 256 + w * 64;
  const float cE = 0.17677669529f * 1.44269504089f;   // scale * log2(e)

  for (int pr = 0; pr < 32; ++pr) {
    const int qa = q0 + pr * 2, qb = qa + 1;
    // q vectors (lane-uniform loads, cached)
    u32 Aq[16], Bq[16];
    const u32* qau = (const u32*)(qbuf + base + (size_t)qa * 32);
    const u32* qbu = (const u32*)(qbuf + base + (size_t)qb * 32);
#pragma unroll
    for (int t = 0; t < 16; ++t) { Aq[t] = qau[t]; Bq[t] = qbu[t]; }

    // ---- scores: lane l handles keys 8l..8l+7 ----
    float sA[8] = {0.f}, sB[8] = {0.f};
#pragma unroll
    for (int dp = 0; dp < 16; ++dp) {
      const float qa0 = bfl(Aq[dp]), qa1 = bfh(Aq[dp]);
      const float qb0 = bfl(Bq[dp]), qb1 = bfh(Bq[dp]);
      const uint4 k0 = *(const uint4*)&KT[(2*dp)   * 512 + 8 * l];
      const uint4 k1 = *(const uint4*)&KT[(2*dp+1) * 512 + 8 * l];
      float f0[8], f1[8]; unp8(k0, f0); unp8(k1, f1);
#pragma unroll
      for (int j = 0; j < 8; ++j) {
        sA[j] += f0[j] * qa0 + f1[j] * qa1;
        sB[j] += f0[j] * qb0 + f1[j] * qb1;
      }
    }

    // ---- softmax (64-lane reductions) ----
    float mA = sA[0], mB = sB[0];
#pragma unroll
    for (int j = 1; j < 8; ++j) { mA = fmaxf(mA, sA[j]); mB = fmaxf(mB, sB[j]); }
#pragma unroll
    for (int m = 1; m < 64; m <<= 1) { mA = fmaxf(mA, __shfl_xor(mA, m)); mB = fmaxf(mB, __shfl_xor(mB, m)); }
    float suA = 0.f, suB = 0.f;
#pragma unroll
    for (int j = 0; j < 8; ++j) {
      sA[j] = exp2f((sA[j] - mA) * cE); suA += sA[j];
      sB[j] = exp2f((sB[j] - mB) * cE); suB += sB[j];
    }
#pragma unroll
    for (int m = 1; m < 64; m <<= 1) { suA += __shfl_xor(suA, m); suB += __shfl_xor(suB, m); }
    const float invA = 1.f / suA, invB = 1.f / suB;

    // ---- PV: lane covers dims (2*d2h, 2*d2h+1), key-quarter c ----
    float aAx = 0.f, aAy = 0.f, aBx = 0.f, aBy = 0.f;
#pragma unroll
    for (int j = 0; j < 8; ++j) {
      const float paj = sA[j], pbj = sB[j];
#pragma unroll
      for (int i = 0; i < 16; ++i) {
        const int m = c * 16 + ((i + c) & 15);    // stagger per quarter (bank spread)
        const float pa = __shfl(paj, m);          // p of key 8m+j (held by lane m)
        const float pb = __shfl(pbj, m);
        const u32 v2 = V2[d2h * 512 + 8 * m + j];
        const float v0 = bfl(v2), v1 = bfh(v2);
        aAx += pa * v0; aAy += pa * v1;
        aBx += pb * v0; aBy += pb * v1;
      }
    }
    // reduce across the 4 quarters
    aAx += __shfl_xor(aAx, 16); aAy += __shfl_xor(aAy, 16);
    aBx += __shfl_xor(aBx, 16); aBy += __shfl_xor(aBy, 16);
    aAx += __shfl_xor(aAx, 32); aAy += __shfl_xor(aAy, 32);
    aBx += __shfl_xor(aBx, 32); aBy += __shfl_xor(aBy, 32);

    if (c < 2) {
      const int qq  = c ? qb : qa;
      const float fx = (c ? aBx : aAx) * (c ? invB : invA);
      const float fy = (c ? aBy : aAy) * (c ? invB : invA);
      const u32 pk = (u32)f2b(fx) | ((u32)f2b(fy) << 16);
      const int b = bh >> 3, h = bh & 7;
      ((u32*)ctx)[ (size_t)(b * 512 + qq) * 128 + h * 16 + d2h ] = pk;
    }
  }
}

// ============================================================
// Kernel 3: out-proj + residual + sqrt(1/2) scale. 8 rows/block.
// ============================================================
template<int F32>
__global__ __launch_bounds__(256) void proj_kernel(
    const u16* __restrict__ ctx, const void* __restrict__ xin,
    const void* __restrict__ wo, void* __restrict__ out)
{
  if (sniff_mode(xin) != F32) return;

  __shared__ __align__(16) float cx[8][256];
  const int tid = threadIdx.x;
  // stage 8 rows (2048 bf16 contiguous)
  const uint4 t4 = ((const uint4*)(ctx + (size_t)blockIdx.x * 2048))[tid];
  {
    const int e = tid * 8, r = e >> 8, col = e & 255;
    float f[8]; unp8(t4, f);
    float4* dst = (float4*)&cx[r][col];
    dst[0] = make_float4(f[0], f[1], f[2], f[3]);
    dst[1] = make_float4(f[4], f[5], f[6], f[7]);
  }
  __syncthreads();

  float acc[8] = {0.f};
  for (int i8 = 0; i8 < 32; ++i8) {
    float wf[8]; load8<F32>(wo, tid * 32 + i8, wf);
    const int i = i8 * 8;
#pragma unroll
    for (int rr = 0; rr < 8; ++rr) {
      const float4 xa = *(const float4*)&cx[rr][i];
      const float4 xb = *(const float4*)&cx[rr][i + 4];
      acc[rr] += xa.x*wf[0] + xa.y*wf[1] + xa.z*wf[2] + xa.w*wf[3]
               + xb.x*wf[4] + xb.y*wf[5] + xb.z*wf[6] + xb.w*wf[7];
    }
  }
  const size_t ob = (size_t)blockIdx.x * 2048 + tid;
#pragma unroll
  for (int rr = 0; rr < 8; ++rr) {
    const float xi = load1<F32>(xin, ob + rr * 256);
    store1<F32>(out, ob + rr * 256, (acc[rr] + xi) * 0.70710678f);
  }
}

// ============================================================
extern "C" void kernel_launch(void* const* d_in, const int* in_sizes, int n_in,
                              void* d_out, int out_size, void* d_ws, size_t ws_size,
                              hipStream_t stream)
{
  const void* xin   = d_in[0];  // inputs      [32,512,256]
  const void* rmask = d_in[1];  // radial_mask [32,512]
  const void* wi    = d_in[2];  // in_proj_w   [768,256]
  const void* wo    = d_in[3];  // out_proj_w  [256,256]
  const void* gam   = d_in[4];  // ln_gamma    [256]
  const void* bet   = d_in[5];  // ln_beta     [256]

  u16* q   = (u16*)d_ws;                   // [256][512][32] bf16  (8 MB)
  u16* k   = q + 4194304;
  u16* v   = k + 4194304;
  u16* cxb = v + 4194304;                  // ctx [32,512,256] bf16 (8 MB)

  ln_qkv_kernel<0><<<2048, 256, 0, stream>>>(xin, rmask, wi, gam, bet, q, k, v);
  ln_qkv_kernel<1><<<2048, 256, 0, stream>>>(xin, rmask, wi, gam, bet, q, k, v);
  attn_kernel     <<<512,  256, 0, stream>>>(q, k, v, cxb);
  proj_kernel<0>  <<<2048, 256, 0, stream>>>(cxb, xin, wo, d_out);
  proj_kernel<1>  <<<2048, 256, 0, stream>>>(cxb, xin, wo, d_out);
}

// Round 3
// 541.719 us; speedup vs baseline: 1.9417x; 1.9417x over previous
//
#include <hip/hip_runtime.h>
#include <hip/hip_bf16.h>

typedef unsigned int u32;
typedef unsigned short u16;

#define B_   32
#define S_   512
#define H_   256
#define NH_  8
#define HD_  32

typedef __attribute__((ext_vector_type(8))) short short8;
typedef __attribute__((ext_vector_type(4))) float f32x4;

// ---------- bf16 helpers (bf16 = high 16 bits of f32) ----------
__device__ __forceinline__ float bfl(u32 u){ union{u32 i;float f;} c; c.i = u << 16;          return c.f; }
__device__ __forceinline__ float bfh(u32 u){ union{u32 i;float f;} c; c.i = u & 0xffff0000u;  return c.f; }
__device__ __forceinline__ float bf1(u16 u){ union{u32 i;float f;} c; c.i = ((u32)u) << 16;   return c.f; }
__device__ __forceinline__ u16   f2b(float f){ __hip_bfloat16 h = __float2bfloat16(f); return *reinterpret_cast<u16*>(&h); }
__device__ __forceinline__ void  unp8(const uint4 u, float* f){
  f[0]=bfl(u.x); f[1]=bfh(u.x); f[2]=bfl(u.y); f[3]=bfh(u.y);
  f[4]=bfl(u.z); f[5]=bfh(u.z); f[6]=bfl(u.w); f[7]=bfh(u.w);
}

__device__ __forceinline__ f32x4 mfma16(short8 a, short8 b, f32x4 c){
  return __builtin_amdgcn_mfma_f32_16x16x32_bf16(a, b, c, 0, 0, 0);
}

// ---------- dtype-polymorphic loads (F32=1: float data, F32=0: bf16 data) ----------
template<int F32>
__device__ __forceinline__ void load8(const void* p, int e8, float* f) {
  if (F32) {
    const float4* q = (const float4*)p;
    const float4 a = q[e8 * 2], b = q[e8 * 2 + 1];
    f[0]=a.x; f[1]=a.y; f[2]=a.z; f[3]=a.w; f[4]=b.x; f[5]=b.y; f[6]=b.z; f[7]=b.w;
  } else {
    unp8(((const uint4*)p)[e8], f);
  }
}
template<int F32>
__device__ __forceinline__ float load1(const void* p, size_t e) {
  return F32 ? ((const float*)p)[e] : bf1(((const u16*)p)[e]);
}
template<int F32>
__device__ __forceinline__ void store1(void* p, size_t e, float v) {
  if (F32) ((float*)p)[e] = v; else ((u16*)p)[e] = f2b(v);
}

// ---------- in-kernel dtype sniff over first 4KB of `inputs` ----------
__device__ __forceinline__ int sniff_mode(const void* xin) {   // 0=bf16, 1=f32
  __shared__ int votes;
  const int tid = threadIdx.x;
  if (tid == 0) votes = 0;
  __syncthreads();
  const u32* xw = (const u32*)xin;
  int h = 0;
#pragma unroll
  for (int j = 0; j < 4; ++j) {
    const u32 u = xw[(tid << 2) + j];
    const u32 e = (u >> 7) & 0xFF;
    h += (e >= 100 && e <= 135) ? 1 : 0;
  }
  if (h) atomicAdd(&votes, h);
  __syncthreads();
  return (votes >= 512) ? 0 : 1;
}

// ============================================================
// Kernel 1: LayerNorm + QKV proj + head transforms.
// 8 rows/block, 256 threads. q,k: [bh][s][d] bf16. v: TRANSPOSED [bh][d][s].
// ============================================================
template<int F32>
__global__ __launch_bounds__(256) void ln_qkv_kernel(
    const void* __restrict__ xin, const void* __restrict__ rmask,
    const void* __restrict__ wi, const void* __restrict__ gamma,
    const void* __restrict__ beta,
    u16* __restrict__ qbuf, u16* __restrict__ kbuf, u16* __restrict__ vt)
{
  if (sniff_mode(xin) != F32) return;

  __shared__ __align__(16) float xn[8][256];
  __shared__ float lmr[8];
  const int tid = threadIdx.x;
  const int r   = tid >> 5;
  const int ln  = tid & 31;
  const int grow = blockIdx.x * 8 + r;

  float x[8]; load8<F32>(xin, grow * 32 + ln, x);
  float s = 0.f, sq = 0.f;
#pragma unroll
  for (int j = 0; j < 8; ++j) { s += x[j]; sq += x[j] * x[j]; }
#pragma unroll
  for (int m = 1; m < 32; m <<= 1) { s += __shfl_xor(s, m); sq += __shfl_xor(sq, m); }
  const float mu  = s * (1.f / 256.f);
  const float var = sq * (1.f / 256.f) - mu * mu;
  const float rs  = rsqrtf(var + 1e-5f);
  float g[8], bb[8];
  load8<F32>(gamma, ln, g);
  load8<F32>(beta,  ln, bb);
#pragma unroll
  for (int j = 0; j < 8; ++j) xn[r][ln * 8 + j] = (x[j] - mu) * rs * g[j] + bb[j];
  if (ln == 0) lmr[r] = logf(load1<F32>(rmask, grow));
  __syncthreads();

  float acc0[8] = {0.f}, acc1[8] = {0.f}, acc2[8] = {0.f};
  const int ro0 = tid * 32, ro1 = (tid + 256) * 32, ro2 = (tid + 512) * 32;
  for (int i8 = 0; i8 < 32; ++i8) {
    float wq8[8], wk8[8], wv8[8];
    load8<F32>(wi, ro0 + i8, wq8);
    load8<F32>(wi, ro1 + i8, wk8);
    load8<F32>(wi, ro2 + i8, wv8);
    const int i = i8 * 8;
#pragma unroll
    for (int rr = 0; rr < 8; ++rr) {
      const float4 xa = *(const float4*)&xn[rr][i];
      const float4 xb = *(const float4*)&xn[rr][i + 4];
      acc0[rr] += xa.x*wq8[0] + xa.y*wq8[1] + xa.z*wq8[2] + xa.w*wq8[3]
                + xb.x*wq8[4] + xb.y*wq8[5] + xb.z*wq8[6] + xb.w*wq8[7];
      acc1[rr] += xa.x*wk8[0] + xa.y*wk8[1] + xa.z*wk8[2] + xa.w*wk8[3]
                + xb.x*wk8[4] + xb.y*wk8[5] + xb.z*wk8[6] + xb.w*wk8[7];
      acc2[rr] += xa.x*wv8[0] + xa.y*wv8[1] + xa.z*wv8[2] + xa.w*wv8[3]
                + xb.x*wv8[4] + xb.y*wv8[5] + xb.z*wv8[6] + xb.w*wv8[7];
    }
  }

  const int head = tid >> 5, d = tid & 31;
  const int bb_  = blockIdx.x >> 6;          // batch (64 blocks per batch)
  const int ss0  = (blockIdx.x & 63) * 8;    // first row within batch
  const int bh   = bb_ * NH_ + head;
#pragma unroll
  for (int rr = 0; rr < 8; ++rr) {
    const size_t base = ((size_t)bh * S_ + (ss0 + rr)) * HD_ + d;
    float qv = acc0[rr]; qv = qv * qv + 1e-6f;
    qbuf[base] = f2b(qv);
    kbuf[base] = f2b(acc1[rr] + lmr[rr]);
  }
  // v transposed: [bh][d][s], 8 consecutive s -> one dwordx4
  u32 v01 = (u32)f2b(acc2[0]) | ((u32)f2b(acc2[1]) << 16);
  u32 v23 = (u32)f2b(acc2[2]) | ((u32)f2b(acc2[3]) << 16);
  u32 v45 = (u32)f2b(acc2[4]) | ((u32)f2b(acc2[5]) << 16);
  u32 v67 = (u32)f2b(acc2[6]) | ((u32)f2b(acc2[7]) << 16);
  uint4 vv; vv.x = v01; vv.y = v23; vv.z = v45; vv.w = v67;
  *(uint4*)(vt + (size_t)bh * (S_ * HD_) + d * S_ + ss0) = vv;
}

// ============================================================
// Kernel 2: MFMA flash attention. Grid 512 = (bh, s-half), 256 thr.
// K staged in LDS (32KB); V^T read from global; P via wave-private
// double-buffered LDS round-trip (C-layout -> A-layout).
// ============================================================
__global__ __launch_bounds__(256, 2) void attn_mfma(
    const u16* __restrict__ qbuf, const u16* __restrict__ kbuf,
    const u16* __restrict__ vt, u16* __restrict__ ctx)
{
  __shared__ __align__(16) u16 Kl[S_ * HD_];        // 32 KB
  __shared__ __align__(16) u16 Pb[4 * 2 * 16 * 40]; // 10 KB: wave x dbuf x 16 x 40 (80B-stride rows)
  const int tid = threadIdx.x;
  const int bh = blockIdx.x >> 1, sh = blockIdx.x & 1;
  const int l = tid & 63, w = tid >> 6;
  const int lr = l & 15, quad = l >> 4;
  const size_t kvbase = (size_t)bh * (S_ * HD_);

  // stage K (straight copy, coalesced 16B)
  {
    const uint4* ks = (const uint4*)(kbuf + kvbase);
    uint4* kd = (uint4*)Kl;
#pragma unroll
    for (int it = 0; it < 8; ++it) kd[it * 256 + tid] = ks[it * 256 + tid];
  }
  __syncthreads();

  const float cE = 0.17677669529663688f * 1.4426950408889634f; // (1/sqrt(32))*log2(e)
  u16* pw = Pb + w * (2 * 16 * 40);
  const int b = bh >> 3, h = bh & 7;
  const u16* vrow0 = vt + kvbase + (size_t)lr * S_;          // dim = lr
  const u16* vrow1 = vt + kvbase + (size_t)(16 + lr) * S_;   // dim = 16+lr

  for (int qt = 0; qt < 4; ++qt) {
    const int q0 = sh * 256 + w * 64 + qt * 16;

    // B-frag: Q[q0+lr][quad*8 .. +7] straight from global
    const short8 qf = *(const short8*)(qbuf + kvbase + (size_t)(q0 + lr) * HD_ + quad * 8);

    // ---- QK^T: S^T tiles, A=K, B=Q. acc[kt] row=key(quad*4+r), col=query(lr) ----
    f32x4 acc[32];
#pragma unroll
    for (int kt = 0; kt < 32; ++kt) {
      const short8 kf = *(const short8*)(Kl + (kt * 16 + lr) * HD_ + quad * 8);
      f32x4 z = {0.f, 0.f, 0.f, 0.f};
      acc[kt] = mfma16(kf, qf, z);
    }

    // ---- softmax over keys for query col=lr ----
    float mx = -1e30f;
#pragma unroll
    for (int kt = 0; kt < 32; ++kt) {
#pragma unroll
      for (int r = 0; r < 4; ++r) mx = fmaxf(mx, acc[kt][r]);
    }
    mx = fmaxf(mx, __shfl_xor(mx, 16));
    mx = fmaxf(mx, __shfl_xor(mx, 32));
    const float mE = mx * cE;
    float sum = 0.f;
#pragma unroll
    for (int kt = 0; kt < 32; ++kt) {
#pragma unroll
      for (int r = 0; r < 4; ++r) {
        const float p = exp2f(fmaf(acc[kt][r], cE, -mE));
        acc[kt][r] = p; sum += p;
      }
    }
    sum += __shfl_xor(sum, 16);
    sum += __shfl_xor(sum, 32);
    const float inv = 1.f / sum;   // valid per query=lr (replicated over quads)

    // ---- PV: A=P (LDS round-trip), B=V^T (global). out rows=query, cols=dim ----
    f32x4 o0 = {0.f,0.f,0.f,0.f}, o1 = {0.f,0.f,0.f,0.f};
#pragma unroll
    for (int c = 0; c < 16; ++c) {
      u16* pbuf = pw + (c & 1) * (16 * 40);
      // write P chunk (keys 32c..32c+31): C-layout -> rows=query(lr), key offset t*16+quad*4+r
#pragma unroll
      for (int t = 0; t < 2; ++t) {
        const int kt = 2 * c + t;
        uint2 pk;
        pk.x = (u32)f2b(acc[kt][0]) | ((u32)f2b(acc[kt][1]) << 16);
        pk.y = (u32)f2b(acc[kt][2]) | ((u32)f2b(acc[kt][3]) << 16);
        *(uint2*)(pbuf + lr * 40 + t * 16 + quad * 4) = pk;
      }
      // read back as A-frag: A[m=query=lr][k=quad*8+j]
      const short8 pa = *(const short8*)(pbuf + lr * 40 + quad * 8);
      const short8 v0 = *(const short8*)(vrow0 + c * 32 + quad * 8);
      const short8 v1 = *(const short8*)(vrow1 + c * 32 + quad * 8);
      o0 = mfma16(pa, v0, o0);
      o1 = mfma16(pa, v1, o1);
    }

    // ---- epilogue: /sum per query row, store ctx[b][s][h*32+d] ----
#pragma unroll
    for (int r = 0; r < 4; ++r) {
      const int qq = quad * 4 + r;
      const float iv = __shfl(inv, (l & 48) | qq);
      u16* dst = ctx + ((size_t)(b * S_ + q0 + qq)) * H_ + h * HD_;
      dst[lr]      = f2b(o0[r] * iv);
      dst[16 + lr] = f2b(o1[r] * iv);
    }
  }
}

// ============================================================
// Kernel 3: out-proj + residual + sqrt(1/2). 8 rows/block.
// ============================================================
template<int F32>
__global__ __launch_bounds__(256) void proj_kernel(
    const u16* __restrict__ ctx, const void* __restrict__ xin,
    const void* __restrict__ wo, void* __restrict__ out)
{
  if (sniff_mode(xin) != F32) return;

  __shared__ __align__(16) float cx[8][256];
  const int tid = threadIdx.x;
  const uint4 t4 = ((const uint4*)(ctx + (size_t)blockIdx.x * 2048))[tid];
  {
    const int e = tid * 8, r = e >> 8, col = e & 255;
    float f[8]; unp8(t4, f);
    float4* dst = (float4*)&cx[r][col];
    dst[0] = make_float4(f[0], f[1], f[2], f[3]);
    dst[1] = make_float4(f[4], f[5], f[6], f[7]);
  }
  __syncthreads();

  float acc[8] = {0.f};
  for (int i8 = 0; i8 < 32; ++i8) {
    float wf[8]; load8<F32>(wo, tid * 32 + i8, wf);
    const int i = i8 * 8;
#pragma unroll
    for (int rr = 0; rr < 8; ++rr) {
      const float4 xa = *(const float4*)&cx[rr][i];
      const float4 xb = *(const float4*)&cx[rr][i + 4];
      acc[rr] += xa.x*wf[0] + xa.y*wf[1] + xa.z*wf[2] + xa.w*wf[3]
               + xb.x*wf[4] + xb.y*wf[5] + xb.z*wf[6] + xb.w*wf[7];
    }
  }
  const size_t ob = (size_t)blockIdx.x * 2048 + tid;
#pragma unroll
  for (int rr = 0; rr < 8; ++rr) {
    const float xi = load1<F32>(xin, ob + rr * 256);
    store1<F32>(out, ob + rr * 256, (acc[rr] + xi) * 0.70710678f);
  }
}

// ============================================================
extern "C" void kernel_launch(void* const* d_in, const int* in_sizes, int n_in,
                              void* d_out, int out_size, void* d_ws, size_t ws_size,
                              hipStream_t stream)
{
  const void* xin   = d_in[0];
  const void* rmask = d_in[1];
  const void* wi    = d_in[2];
  const void* wo    = d_in[3];
  const void* gam   = d_in[4];
  const void* bet   = d_in[5];

  u16* q   = (u16*)d_ws;                   // [256][512][32] bf16 (8 MB)
  u16* k   = q + 4194304;
  u16* vt  = k + 4194304;                  // transposed [256][32][512] (8 MB)
  u16* cxb = vt + 4194304;                 // ctx [32,512,256] bf16 (8 MB)

  ln_qkv_kernel<0><<<2048, 256, 0, stream>>>(xin, rmask, wi, gam, bet, q, k, vt);
  ln_qkv_kernel<1><<<2048, 256, 0, stream>>>(xin, rmask, wi, gam, bet, q, k, vt);
  attn_mfma       <<<512,  256, 0, stream>>>(q, k, vt, cxb);
  proj_kernel<0>  <<<2048, 256, 0, stream>>>(cxb, xin, wo, d_out);
  proj_kernel<1>  <<<2048, 256, 0, stream>>>(cxb, xin, wo, d_out);
}

// Round 4
// 237.492 us; speedup vs baseline: 4.4291x; 2.2810x over previous
//
#include <hip/hip_runtime.h>
#include <hip/hip_bf16.h>

typedef unsigned int u32;
typedef unsigned short u16;

#define B_   32
#define S_   512
#define H_   256
#define NH_  8
#define HD_  32

typedef __attribute__((ext_vector_type(8))) short short8;
typedef __attribute__((ext_vector_type(4))) float f32x4;

// ---------- bf16 helpers ----------
__device__ __forceinline__ float bfl(u32 u){ union{u32 i;float f;} c; c.i = u << 16;          return c.f; }
__device__ __forceinline__ float bfh(u32 u){ union{u32 i;float f;} c; c.i = u & 0xffff0000u;  return c.f; }
__device__ __forceinline__ float bf1(u16 u){ union{u32 i;float f;} c; c.i = ((u32)u) << 16;   return c.f; }
__device__ __forceinline__ u16   f2b(float f){ __hip_bfloat16 h = __float2bfloat16(f); return *reinterpret_cast<u16*>(&h); }
__device__ __forceinline__ void  unp8(const uint4 u, float* f){
  f[0]=bfl(u.x); f[1]=bfh(u.x); f[2]=bfl(u.y); f[3]=bfh(u.y);
  f[4]=bfl(u.z); f[5]=bfh(u.z); f[6]=bfl(u.w); f[7]=bfh(u.w);
}
__device__ __forceinline__ f32x4 mfma16(short8 a, short8 b, f32x4 c){
  return __builtin_amdgcn_mfma_f32_16x16x32_bf16(a, b, c, 0, 0, 0);
}

// ---------- dtype-polymorphic loads ----------
template<int F32>
__device__ __forceinline__ void load8(const void* p, int e8, float* f) {
  if (F32) {
    const float4* q = (const float4*)p;
    const float4 a = q[e8 * 2], b = q[e8 * 2 + 1];
    f[0]=a.x; f[1]=a.y; f[2]=a.z; f[3]=a.w; f[4]=b.x; f[5]=b.y; f[6]=b.z; f[7]=b.w;
  } else {
    unp8(((const uint4*)p)[e8], f);
  }
}
template<int F32>
__device__ __forceinline__ float load1(const void* p, size_t e) {
  return F32 ? ((const float*)p)[e] : bf1(((const u16*)p)[e]);
}
template<int F32>
__device__ __forceinline__ void store1(void* p, size_t e, float v) {
  if (F32) ((float*)p)[e] = v; else ((u16*)p)[e] = f2b(v);
}
// B-fragment: 8 consecutive k of W[row][k0..k0+7] as bf16 short8
template<int F32>
__device__ __forceinline__ short8 loadBfrag(const void* wp, int row, int k0, int K) {
  if (F32) {
    const float* w = (const float*)wp + (size_t)row * K + k0;
    const float4 a = *(const float4*)w;
    const float4 b = *(const float4*)(w + 4);
    short8 r;
    r[0]=(short)f2b(a.x); r[1]=(short)f2b(a.y); r[2]=(short)f2b(a.z); r[3]=(short)f2b(a.w);
    r[4]=(short)f2b(b.x); r[5]=(short)f2b(b.y); r[6]=(short)f2b(b.z); r[7]=(short)f2b(b.w);
    return r;
  } else {
    return *(const short8*)((const u16*)wp + (size_t)row * K + k0);
  }
}

// ---------- dtype sniff (first 4KB of `inputs`) ----------
__device__ __forceinline__ int sniff_mode(const void* xin) {   // 0=bf16, 1=f32
  __shared__ int votes;
  const int tid = threadIdx.x;
  if (tid == 0) votes = 0;
  __syncthreads();
  const u32* xw = (const u32*)xin;
  int h = 0;
#pragma unroll
  for (int j = 0; j < 4; ++j) {
    const u32 u = xw[(tid << 2) + j];
    const u32 e = (u >> 7) & 0xFF;
    h += (e >= 100 && e <= 135) ? 1 : 0;
  }
  if (h) atomicAdd(&votes, h);
  __syncthreads();
  return (votes >= 512) ? 0 : 1;
}

// ============================================================
// Kernel 1: LN + QKV via MFMA. Grid 512 (M=32 rows/block), 256 thr.
// Phase A: LN -> A-frag-major LDS. Phase B: wave = 12 n-tiles x 2 m-tiles.
// q,k: [bh][s][d]; v transposed [bh][d][s].
// ============================================================
template<int F32>
__global__ __launch_bounds__(256) void ln_qkv_mfma(
    const void* __restrict__ xin, const void* __restrict__ rmask,
    const void* __restrict__ wi, const void* __restrict__ gamma,
    const void* __restrict__ beta,
    u16* __restrict__ qbuf, u16* __restrict__ kbuf, u16* __restrict__ vt)
{
  if (sniff_mode(xin) != F32) return;

  __shared__ __align__(16) u16 XnF[2 * 8 * 64 * 8];   // [mtile][kchunk][lane][8] = 16 KB
  __shared__ float lmr[32];
  const int tid = threadIdx.x;
  const int l = tid & 63, w = tid >> 6;
  const int lr = l & 15, quad = l >> 4;
  const int row0 = blockIdx.x * 32;                   // rows in flat [B*S]

  // ---- Phase A: LayerNorm, frag-major store ----
  {
    const int r = tid >> 5, ln = tid & 31;
    float g[8], bb[8];
    load8<F32>(gamma, ln, g);
    load8<F32>(beta,  ln, bb);
    const int c = ln >> 2, qd = ln & 3;
#pragma unroll
    for (int p = 0; p < 4; ++p) {
      const int R = p * 8 + r;                        // local row 0..31
      const int grow = row0 + R;
      float x[8]; load8<F32>(xin, grow * 32 + ln, x);
      float s = 0.f, sq = 0.f;
#pragma unroll
      for (int j = 0; j < 8; ++j) { s += x[j]; sq += x[j] * x[j]; }
#pragma unroll
      for (int m = 1; m < 32; m <<= 1) { s += __shfl_xor(s, m); sq += __shfl_xor(sq, m); }
      const float mu  = s * (1.f / 256.f);
      const float var = sq * (1.f / 256.f) - mu * mu;
      const float rs  = rsqrtf(var + 1e-5f);
      short8 pk;
#pragma unroll
      for (int j = 0; j < 8; ++j) pk[j] = (short)f2b((x[j] - mu) * rs * g[j] + bb[j]);
      const int t = R >> 4, rm = R & 15;
      *(short8*)(XnF + (((t * 8 + c) * 64 + qd * 16 + rm) << 3)) = pk;
      if (ln == 0) lmr[R] = logf(load1<F32>(rmask, grow));
    }
  }
  __syncthreads();

  // ---- Phase B: GEMM. wave w: n-tiles w*12 .. w*12+11 over 768 outputs ----
  const int bb_ = row0 >> 9;                 // batch
  const int sB  = (row0 & 511);              // s base of block
  for (int nt = 0; nt < 12; ++nt) {
    const int nAbs = (w * 12 + nt) * 16;     // 0..752
    short8 Bf[8];
#pragma unroll
    for (int c = 0; c < 8; ++c) Bf[c] = loadBfrag<F32>(wi, nAbs + lr, c * 32 + quad * 8, 256);

    f32x4 a0 = {0.f,0.f,0.f,0.f}, a1 = {0.f,0.f,0.f,0.f};
#pragma unroll
    for (int c = 0; c < 8; ++c) {
      const short8 f0 = *(const short8*)(XnF + ((c       * 64 + l) << 3));
      const short8 f1 = *(const short8*)(XnF + (((8 + c) * 64 + l) << 3));
      a0 = mfma16(f0, Bf[c], a0);
      a1 = mfma16(f1, Bf[c], a1);
    }

    const int type = nAbs >> 8;              // 0=q 1=k 2=v
    const int d    = (nAbs & 255) + lr;
    const int h    = d >> 5, dd = d & 31;
    const int bh   = bb_ * NH_ + h;
#pragma unroll
    for (int m = 0; m < 2; ++m) {
      const f32x4 acc = m ? a1 : a0;
      const int sLoc = m * 16 + quad * 4;    // local row of acc[0]
      if (type == 0) {
#pragma unroll
        for (int i = 0; i < 4; ++i) {
          float qv = acc[i]; qv = qv * qv + 1e-6f;
          qbuf[((size_t)bh * S_ + (sB + sLoc + i)) * HD_ + dd] = f2b(qv);
        }
      } else if (type == 1) {
#pragma unroll
        for (int i = 0; i < 4; ++i)
          kbuf[((size_t)bh * S_ + (sB + sLoc + i)) * HD_ + dd] = f2b(acc[i] + lmr[sLoc + i]);
      } else {
        uint2 pk;
        pk.x = (u32)f2b(acc[0]) | ((u32)f2b(acc[1]) << 16);
        pk.y = (u32)f2b(acc[2]) | ((u32)f2b(acc[3]) << 16);
        *(uint2*)(vt + ((size_t)bh * HD_ + dd) * S_ + sB + sLoc) = pk;
      }
    }
  }
}

// ============================================================
// Kernel 2: MFMA flash attention (unchanged from R3).
// ============================================================
__global__ __launch_bounds__(256, 2) void attn_mfma(
    const u16* __restrict__ qbuf, const u16* __restrict__ kbuf,
    const u16* __restrict__ vt, u16* __restrict__ ctx)
{
  __shared__ __align__(16) u16 Kl[S_ * HD_];        // 32 KB
  __shared__ __align__(16) u16 Pb[4 * 2 * 16 * 40]; // 10 KB
  const int tid = threadIdx.x;
  const int bh = blockIdx.x >> 1, sh = blockIdx.x & 1;
  const int l = tid & 63, w = tid >> 6;
  const int lr = l & 15, quad = l >> 4;
  const size_t kvbase = (size_t)bh * (S_ * HD_);

  {
    const uint4* ks = (const uint4*)(kbuf + kvbase);
    uint4* kd = (uint4*)Kl;
#pragma unroll
    for (int it = 0; it < 8; ++it) kd[it * 256 + tid] = ks[it * 256 + tid];
  }
  __syncthreads();

  const float cE = 0.17677669529663688f * 1.4426950408889634f;
  u16* pw = Pb + w * (2 * 16 * 40);
  const int b = bh >> 3, h = bh & 7;
  const u16* vrow0 = vt + kvbase + (size_t)lr * S_;
  const u16* vrow1 = vt + kvbase + (size_t)(16 + lr) * S_;

  for (int qt = 0; qt < 4; ++qt) {
    const int q0 = sh * 256 + w * 64 + qt * 16;
    const short8 qf = *(const short8*)(qbuf + kvbase + (size_t)(q0 + lr) * HD_ + quad * 8);

    f32x4 acc[32];
#pragma unroll
    for (int kt = 0; kt < 32; ++kt) {
      const short8 kf = *(const short8*)(Kl + (kt * 16 + lr) * HD_ + quad * 8);
      f32x4 z = {0.f, 0.f, 0.f, 0.f};
      acc[kt] = mfma16(kf, qf, z);
    }

    float mx = -1e30f;
#pragma unroll
    for (int kt = 0; kt < 32; ++kt) {
#pragma unroll
      for (int r = 0; r < 4; ++r) mx = fmaxf(mx, acc[kt][r]);
    }
    mx = fmaxf(mx, __shfl_xor(mx, 16));
    mx = fmaxf(mx, __shfl_xor(mx, 32));
    const float mE = mx * cE;
    float sum = 0.f;
#pragma unroll
    for (int kt = 0; kt < 32; ++kt) {
#pragma unroll
      for (int r = 0; r < 4; ++r) {
        const float p = exp2f(fmaf(acc[kt][r], cE, -mE));
        acc[kt][r] = p; sum += p;
      }
    }
    sum += __shfl_xor(sum, 16);
    sum += __shfl_xor(sum, 32);
    const float inv = 1.f / sum;

    f32x4 o0 = {0.f,0.f,0.f,0.f}, o1 = {0.f,0.f,0.f,0.f};
#pragma unroll
    for (int c = 0; c < 16; ++c) {
      u16* pbuf = pw + (c & 1) * (16 * 40);
#pragma unroll
      for (int t = 0; t < 2; ++t) {
        const int kt = 2 * c + t;
        uint2 pk;
        pk.x = (u32)f2b(acc[kt][0]) | ((u32)f2b(acc[kt][1]) << 16);
        pk.y = (u32)f2b(acc[kt][2]) | ((u32)f2b(acc[kt][3]) << 16);
        *(uint2*)(pbuf + lr * 40 + t * 16 + quad * 4) = pk;
      }
      const short8 pa = *(const short8*)(pbuf + lr * 40 + quad * 8);
      const short8 v0 = *(const short8*)(vrow0 + c * 32 + quad * 8);
      const short8 v1 = *(const short8*)(vrow1 + c * 32 + quad * 8);
      o0 = mfma16(pa, v0, o0);
      o1 = mfma16(pa, v1, o1);
    }

#pragma unroll
    for (int r = 0; r < 4; ++r) {
      const int qq = quad * 4 + r;
      const float iv = __shfl(inv, (l & 48) | qq);
      u16* dst = ctx + ((size_t)(b * S_ + q0 + qq)) * H_ + h * HD_;
      dst[lr]      = f2b(o0[r] * iv);
      dst[16 + lr] = f2b(o1[r] * iv);
    }
  }
}

// ============================================================
// Kernel 3: out-proj via MFMA + residual + sqrt(1/2).
// Grid 512 (M=32), 256 thr. Wave: 4 n-tiles x 2 m-tiles.
// ============================================================
template<int F32>
__global__ __launch_bounds__(256) void proj_mfma(
    const u16* __restrict__ ctx, const void* __restrict__ xin,
    const void* __restrict__ wo, void* __restrict__ out)
{
  if (sniff_mode(xin) != F32) return;

  __shared__ __align__(16) u16 XnF[2 * 8 * 64 * 8];   // 16 KB
  const int tid = threadIdx.x;
  const int l = tid & 63, w = tid >> 6;
  const int lr = l & 15, quad = l >> 4;
  const int row0 = blockIdx.x * 32;

  // ---- stage ctx rows -> frag-major ----
#pragma unroll
  for (int it = 0; it < 4; ++it) {
    const int idx = it * 256 + tid;          // 0..1023 : 32 rows x 32 uint4
    const int R = idx >> 5, u4 = idx & 31;
    const uint4 cv = ((const uint4*)ctx)[(size_t)row0 * 32 + idx];
    const int t = R >> 4, c = u4 >> 2, qd = u4 & 3, rm = R & 15;
    *(uint4*)(XnF + (((t * 8 + c) * 64 + qd * 16 + rm) << 3)) = cv;
  }
  __syncthreads();

  for (int nt = 0; nt < 4; ++nt) {
    const int n0 = (w * 4 + nt) * 16;
    short8 Bf[8];
#pragma unroll
    for (int c = 0; c < 8; ++c) Bf[c] = loadBfrag<F32>(wo, n0 + lr, c * 32 + quad * 8, 256);

    f32x4 a0 = {0.f,0.f,0.f,0.f}, a1 = {0.f,0.f,0.f,0.f};
#pragma unroll
    for (int c = 0; c < 8; ++c) {
      const short8 f0 = *(const short8*)(XnF + ((c       * 64 + l) << 3));
      const short8 f1 = *(const short8*)(XnF + (((8 + c) * 64 + l) << 3));
      a0 = mfma16(f0, Bf[c], a0);
      a1 = mfma16(f1, Bf[c], a1);
    }

#pragma unroll
    for (int m = 0; m < 2; ++m) {
      const f32x4 acc = m ? a1 : a0;
#pragma unroll
      for (int i = 0; i < 4; ++i) {
        const size_t e = (size_t)(row0 + m * 16 + quad * 4 + i) * H_ + n0 + lr;
        const float xi = load1<F32>(xin, e);
        store1<F32>(out, e, (acc[i] + xi) * 0.70710678f);
      }
    }
  }
}

// ============================================================
extern "C" void kernel_launch(void* const* d_in, const int* in_sizes, int n_in,
                              void* d_out, int out_size, void* d_ws, size_t ws_size,
                              hipStream_t stream)
{
  const void* xin   = d_in[0];
  const void* rmask = d_in[1];
  const void* wi    = d_in[2];
  const void* wo    = d_in[3];
  const void* gam   = d_in[4];
  const void* bet   = d_in[5];

  u16* q   = (u16*)d_ws;                   // [256][512][32] bf16 (8 MB)
  u16* k   = q + 4194304;
  u16* vt  = k + 4194304;                  // transposed [256][32][512] (8 MB)
  u16* cxb = vt + 4194304;                 // ctx [32,512,256] bf16 (8 MB)

  ln_qkv_mfma<0><<<512, 256, 0, stream>>>(xin, rmask, wi, gam, bet, q, k, vt);
  ln_qkv_mfma<1><<<512, 256, 0, stream>>>(xin, rmask, wi, gam, bet, q, k, vt);
  attn_mfma     <<<512, 256, 0, stream>>>(q, k, vt, cxb);
  proj_mfma<0>  <<<512, 256, 0, stream>>>(cxb, xin, wo, d_out);
  proj_mfma<1>  <<<512, 256, 0, stream>>>(cxb, xin, wo, d_out);
}